// Round 1
// baseline (970.183 us; speedup 1.0000x reference)
//
#include <hip/hip_runtime.h>
#include <stdint.h>

#define DIM   2048
#define NEXP  8
#define EDIM  1024
#define NTOK  8192   // B*S = 4*2048

using bf16x8 = __attribute__((ext_vector_type(8))) short;
using f32x4  = __attribute__((ext_vector_type(4))) float;

typedef __attribute__((address_space(3))) void lds_void_t;
typedef const __attribute__((address_space(1))) void gbl_void_t;

__device__ static inline void load_lds16(const void* g, void* l) {
    __builtin_amdgcn_global_load_lds((gbl_void_t*)g, (lds_void_t*)l, 16, 0, 0);
}

// fp32 -> bf16 bits, round-to-nearest-even
__device__ static inline unsigned short f2b(float x) {
    union { float f; unsigned u; } v; v.f = x;
    unsigned r = v.u + 0x7fffu + ((v.u >> 16) & 1u);
    return (unsigned short)(r >> 16);
}

// tanh-approx gelu (matches jax.nn.gelu approximate=True)
__device__ static inline float gelu_f(float x) {
    float u = 0.7978845608028654f * x * (1.0f + 0.044715f * x * x);
    u = fminf(fmaxf(u, -15.0f), 15.0f);
    float e = __expf(2.0f * u);
    float th = (e - 1.0f) / (e + 1.0f);
    return 0.5f * x * (1.0f + th);
}

// ---------------------------------------------------------------------------
// Transpose + cast fp32 [R,C] row-major -> bf16 [C,R] row-major.
// blockIdx.z selects a slab of R*C elements (per-expert planes for Wu).
// ---------------------------------------------------------------------------
__global__ __launch_bounds__(256)
void transpose_cast(const float* __restrict__ in, unsigned short* __restrict__ out,
                    int R, int C) {
    __shared__ float tile[32][33];
    const size_t slab = (size_t)blockIdx.z * R * C;
    in  += slab;
    out += slab;
    const int c0 = blockIdx.x * 32;
    const int r0 = blockIdx.y * 32;
    const int tx = threadIdx.x;   // 0..31
    const int ty = threadIdx.y;   // 0..7
    #pragma unroll
    for (int i = 0; i < 32; i += 8)
        tile[ty + i][tx] = in[(size_t)(r0 + ty + i) * C + c0 + tx];
    __syncthreads();
    #pragma unroll
    for (int i = 0; i < 32; i += 8)
        out[(size_t)(c0 + ty + i) * R + r0 + tx] = f2b(tile[tx][ty + i]);
}

// ---------------------------------------------------------------------------
// Router + x cast: one block per token. Computes softmax(x@Wr + br) and x_bf16.
// ---------------------------------------------------------------------------
__global__ __launch_bounds__(256)
void router_convert(const float* __restrict__ x, const float* __restrict__ Wr,
                    const float* __restrict__ br, unsigned short* __restrict__ xb,
                    float* __restrict__ probs) {
    const int t   = blockIdx.x;
    const int tid = threadIdx.x;
    const float* xr = x + (size_t)t * DIM;
    float s[NEXP];
    #pragma unroll
    for (int e = 0; e < NEXP; ++e) s[e] = 0.f;
    for (int j = tid; j < DIM; j += 256) {
        float v = xr[j];
        xb[(size_t)t * DIM + j] = f2b(v);
        #pragma unroll
        for (int e = 0; e < NEXP; ++e) s[e] += v * Wr[j * NEXP + e];
    }
    // wave reduce (64 lanes)
    #pragma unroll
    for (int e = 0; e < NEXP; ++e)
        #pragma unroll
        for (int off = 32; off > 0; off >>= 1) s[e] += __shfl_down(s[e], off);
    __shared__ float part[4][NEXP];
    const int wave = tid >> 6, lane = tid & 63;
    if (lane == 0) {
        #pragma unroll
        for (int e = 0; e < NEXP; ++e) part[wave][e] = s[e];
    }
    __syncthreads();
    if (tid == 0) {
        float l[NEXP], mx = -1e30f;
        #pragma unroll
        for (int e = 0; e < NEXP; ++e) {
            l[e] = part[0][e] + part[1][e] + part[2][e] + part[3][e] + br[e];
            mx = fmaxf(mx, l[e]);
        }
        float sum = 0.f;
        #pragma unroll
        for (int e = 0; e < NEXP; ++e) { l[e] = __expf(l[e] - mx); sum += l[e]; }
        const float inv = 1.f / sum;
        #pragma unroll
        for (int e = 0; e < NEXP; ++e) probs[t * NEXP + e] = l[e] * inv;
    }
}

// ---------------------------------------------------------------------------
// bf16 GEMM, m97 structure: C[M,N] = A[M,K] * Bt[N,K]^T
// 128x128 tile, BK=32, 256 threads (4 waves, 2x2), 4x4 of 16x16x32 MFMA/wave.
// MODE 1: epilogue = bf16( gelu(acc + bu[col]) * probs[row, col>>10] ) -> H
// MODE 2: epilogue = acc + sum_e probs[row,e]*bd[e,col] + x[row,col] -> fp32 out
// ---------------------------------------------------------------------------
template <int MODE>
__global__ __launch_bounds__(256, 2)
void gemm_bt(const unsigned short* __restrict__ A,
             const unsigned short* __restrict__ Bt,
             int M, int N, int K,
             const float* __restrict__ probs,
             const float* __restrict__ bias,
             const float* __restrict__ xres,
             void* __restrict__ Cout)
{
    __shared__ unsigned short As[128 * 32];
    __shared__ unsigned short Bs[128 * 32];
    const int tid  = threadIdx.x;
    const int wave = tid >> 6;
    const int lane = tid & 63;
    const int wi = wave >> 1, wj = wave & 1;
    const int row0 = blockIdx.y * 128;
    const int col0 = blockIdx.x * 128;

    // staging: 512 16B-chunks per tile; chunk id g -> row g>>2, k-offset (g&3)*8
    const int g0 = wave * 128 + lane;
    const int g1 = g0 + 64;
    const int ar0 = g0 >> 2, ac0 = (g0 & 3) * 8;
    const int ar1 = g1 >> 2, ac1 = (g1 & 3) * 8;

    const unsigned short* pA0 = A  + (size_t)(row0 + ar0) * K + ac0;
    const unsigned short* pA1 = A  + (size_t)(row0 + ar1) * K + ac1;
    const unsigned short* pB0 = Bt + (size_t)(col0 + ar0) * K + ac0;
    const unsigned short* pB1 = Bt + (size_t)(col0 + ar1) * K + ac1;
    unsigned short* dA0 = &As[g0 * 8];
    unsigned short* dA1 = &As[g1 * 8];
    unsigned short* dB0 = &Bs[g0 * 8];
    unsigned short* dB1 = &Bs[g1 * 8];

    const int m = lane & 15;   // row (A) / col (B) within 16
    const int q = lane >> 4;   // k-chunk quad

    f32x4 acc[4][4];
    #pragma unroll
    for (int i = 0; i < 4; ++i)
        #pragma unroll
        for (int j = 0; j < 4; ++j)
            acc[i][j] = (f32x4){0.f, 0.f, 0.f, 0.f};

    for (int k0 = 0; k0 < K; k0 += 32) {
        load_lds16(pA0 + k0, dA0);
        load_lds16(pA1 + k0, dA1);
        load_lds16(pB0 + k0, dB0);
        load_lds16(pB1 + k0, dB1);
        __syncthreads();   // compiler emits vmcnt(0) drain before barrier
        bf16x8 a[4], b[4];
        #pragma unroll
        for (int t = 0; t < 4; ++t)
            a[t] = *(const bf16x8*)&As[(wi * 64 + t * 16 + m) * 32 + q * 8];
        #pragma unroll
        for (int t = 0; t < 4; ++t)
            b[t] = *(const bf16x8*)&Bs[(wj * 64 + t * 16 + m) * 32 + q * 8];
        #pragma unroll
        for (int i = 0; i < 4; ++i)
            #pragma unroll
            for (int j = 0; j < 4; ++j)
                acc[i][j] = __builtin_amdgcn_mfma_f32_16x16x32_bf16(a[i], b[j], acc[i][j], 0, 0, 0);
        __syncthreads();
    }

    // C/D layout (m89-verified): col = lane&15, row = (lane>>4)*4 + reg
    if (MODE == 1) {
        unsigned short* H = (unsigned short*)Cout;
        const int e = col0 >> 10;   // 128-wide tile never crosses an expert boundary
        #pragma unroll
        for (int i = 0; i < 4; ++i) {
            #pragma unroll
            for (int r = 0; r < 4; ++r) {
                const int rowg = row0 + wi * 64 + i * 16 + q * 4 + r;
                const float p = probs[rowg * NEXP + e];
                #pragma unroll
                for (int j = 0; j < 4; ++j) {
                    const int colg = col0 + wj * 64 + j * 16 + m;
                    float v = acc[i][j][r] + bias[colg];   // bu flat index = e*1024+f = colg
                    H[(size_t)rowg * N + colg] = f2b(gelu_f(v) * p);
                }
            }
        }
    } else {
        float* O = (float*)Cout;
        #pragma unroll
        for (int i = 0; i < 4; ++i) {
            #pragma unroll
            for (int r = 0; r < 4; ++r) {
                const int rowg = row0 + wi * 64 + i * 16 + q * 4 + r;
                float p[NEXP];
                #pragma unroll
                for (int e = 0; e < NEXP; ++e) p[e] = probs[rowg * NEXP + e];
                #pragma unroll
                for (int j = 0; j < 4; ++j) {
                    const int colg = col0 + wj * 64 + j * 16 + m;
                    float v = acc[i][j][r];
                    #pragma unroll
                    for (int e = 0; e < NEXP; ++e) v += p[e] * bias[e * DIM + colg];
                    v += xres[(size_t)rowg * DIM + colg];
                    O[(size_t)rowg * N + colg] = v;
                }
            }
        }
    }
}

// ---------------------------------------------------------------------------
// Workspace layout (bytes):
//   xb    bf16 [8192,2048]        @ 0          (33554432)
//   WuT   bf16 [8][1024,2048]     @ 33554432   (33554432)   = Wu[e] transposed
//   WdT   bf16 [2048,8192]        @ 67108864   (33554432)   = Wd flat transposed
//   probs fp32 [8192,8]           @ 100663296  (262144)
//   h     bf16 [8192,8192]        @ 100925440  (134217728)  = probs-scaled gelu(xWu+bu)
// total 235,143,168 B
// ---------------------------------------------------------------------------
extern "C" void kernel_launch(void* const* d_in, const int* in_sizes, int n_in,
                              void* d_out, int out_size, void* d_ws, size_t ws_size,
                              hipStream_t stream) {
    const float* x  = (const float*)d_in[0];
    const float* Wr = (const float*)d_in[1];
    const float* br = (const float*)d_in[2];
    const float* Wu = (const float*)d_in[3];
    const float* bu = (const float*)d_in[4];
    const float* Wd = (const float*)d_in[5];
    const float* bd = (const float*)d_in[6];
    float* out = (float*)d_out;

    char* ws = (char*)d_ws;
    unsigned short* xb    = (unsigned short*)(ws);
    unsigned short* WuT   = (unsigned short*)(ws + 33554432);
    unsigned short* WdT   = (unsigned short*)(ws + 67108864);
    float*          probs = (float*)(ws + 100663296);
    unsigned short* h     = (unsigned short*)(ws + 100925440);

    dim3 tb(32, 8);
    // Wu [e][d=2048][f=1024] -> WuT [e][f=1024][d=2048]  (B^T layout, N=e*1024+f, K=d)
    transpose_cast<<<dim3(EDIM / 32, DIM / 32, NEXP), tb, 0, stream>>>(Wu, WuT, DIM, EDIM);
    // Wd [(e,f)=8192][d=2048] -> WdT [d=2048][(e,f)=8192] (B^T layout, N=d, K=e*1024+f)
    transpose_cast<<<dim3(DIM / 32, (NEXP * EDIM) / 32, 1), tb, 0, stream>>>(Wd, WdT, NEXP * EDIM, DIM);
    // router softmax + x -> bf16
    router_convert<<<NTOK, 256, 0, stream>>>(x, Wr, br, xb, probs);
    // GEMM1: h = bf16( probs_e * gelu(x @ Wu + bu) )   M=8192 N=8192 K=2048
    gemm_bt<1><<<dim3((NEXP * EDIM) / 128, NTOK / 128), 256, 0, stream>>>(
        xb, WuT, NTOK, NEXP * EDIM, DIM, probs, bu, nullptr, h);
    // GEMM2: out = h @ Wd_concat + probs@bd + x        M=8192 N=2048 K=8192
    gemm_bt<2><<<dim3(DIM / 128, NTOK / 128), 256, 0, stream>>>(
        h, WdT, NTOK, DIM, NEXP * EDIM, probs, bd, x, out);
}